// Round 13
// baseline (320.764 us; speedup 1.0000x reference)
//
#include <hip/hip_runtime.h>
#include <hip/hip_bf16.h>
#include <math.h>

#define NB    4096
#define DD    2048
#define CLOC  128
#define PARTS 8
#define FEPS  1e-12f
#define FMARGIN 0.3f
#define NCHUNK 32

typedef short bf16x8 __attribute__((ext_vector_type(8)));   // 8 bf16 bit-patterns (4 VGPRs)
typedef float f32x4 __attribute__((ext_vector_type(4)));

#define GLD16(g, l) __builtin_amdgcn_global_load_lds(                          \
    (const __attribute__((address_space(1))) void*)(g),                        \
    (__attribute__((address_space(3))) void*)(l), 16, 0, 0)

// ---- kernel 1: L2 normalize + split x = H + L, packed [j=k/8][row] ---------
__global__ __launch_bounds__(256) void normalize_pack_kernel(
    const float* __restrict__ x, uint4* __restrict__ Hp, uint4* __restrict__ Lp,
    float* __restrict__ sq) {
  __shared__ float sm[4];
  const int t = threadIdx.x;
  const int lane = t & 63, wid = t >> 6;
  const int r0 = blockIdx.x * 4;
  uint4 hreg[4], lreg[4];
#pragma unroll
  for (int q = 0; q < 4; ++q) {
    const int row = r0 + q;
    const float* xr = x + (size_t)row * DD + 8 * t;
    const float4 a = *(const float4*)xr;
    const float4 b = *(const float4*)(xr + 4);
    float v[8] = {a.x, a.y, a.z, a.w, b.x, b.y, b.z, b.w};
    float ss = 0.f;
#pragma unroll
    for (int j = 0; j < 8; ++j) ss += v[j] * v[j];
    for (int off = 32; off; off >>= 1) ss += __shfl_down(ss, off);
    if (lane == 0) sm[wid] = ss;
    __syncthreads();
    const float tot = sm[0] + sm[1] + sm[2] + sm[3];
    __syncthreads();  // sm reused next q
    const float inv = 1.0f / (sqrtf(tot) + FEPS);
    if (t == 0) sq[row] = tot * inv * inv;
    unsigned int hw[4], lw[4];
#pragma unroll
    for (int jp = 0; jp < 4; ++jp) {
      const float f0 = v[2 * jp] * inv, f1 = v[2 * jp + 1] * inv;
      const __hip_bfloat16 h0 = __float2bfloat16(f0), h1 = __float2bfloat16(f1);
      const float l0 = f0 - __bfloat162float(h0);
      const float l1 = f1 - __bfloat162float(h1);
      const __hip_bfloat16 g0 = __float2bfloat16(l0), g1 = __float2bfloat16(l1);
      hw[jp] = (unsigned)__builtin_bit_cast(unsigned short, h0) |
               ((unsigned)__builtin_bit_cast(unsigned short, h1) << 16);
      lw[jp] = (unsigned)__builtin_bit_cast(unsigned short, g0) |
               ((unsigned)__builtin_bit_cast(unsigned short, g1) << 16);
    }
    hreg[q] = make_uint4(hw[0], hw[1], hw[2], hw[3]);
    lreg[q] = make_uint4(lw[0], lw[1], lw[2], lw[3]);
  }
  uint4* hd = Hp + (size_t)t * NB + r0;
  uint4* ld = Lp + (size_t)t * NB + r0;
#pragma unroll
  for (int q = 0; q < 4; ++q) { hd[q] = hreg[q]; ld[q] = lreg[q]; }
}

// ---- kernel 2: symmetric split-bf16 MFMA Gram + dual (row+col) mining ------
// Lower-triangle tiles only: block t -> (I,J), J<=I; 528 blocks.
// Each tile mines its rows (cols J -> chunk J) and, when I!=J, its cols
// (rows I -> chunk I, transposed reduce). K-loop/staging identical to the
// verified round-10 kernel.
#define BMT 128
#define KSTEP 32
#define NKT (DD / KSTEP)   // 64
#define NTILES ((NB / BMT) * (NB / BMT + 1) / 2)  // 32*33/2 = 528

__global__ __launch_bounds__(256, 2) void dist_mine_mfma(
    const uint4* __restrict__ Hp, const uint4* __restrict__ Lp,
    const float* __restrict__ sq, const int* __restrict__ targets,
    float* __restrict__ pap, int* __restrict__ papi,
    float* __restrict__ pan, int* __restrict__ pani) {
  __shared__ __attribute__((aligned(16))) char lds[2][32768];
  __shared__ float rowv[2][2][BMT];  // [pos/neg][wc][row_local]
  __shared__ int   rowi[2][2][BMT];
  __shared__ float colv[2][2][BMT];  // [pos/neg][wr][col_local]
  __shared__ int   coli[2][2][BMT];
  const int tid = threadIdx.x;
  const int lane = tid & 63;
  const int w = tid >> 6;
  const int wr = w >> 1, wc = w & 1;
  const int g = lane >> 4, cl = lane & 15;

  // triangular decode: blockIdx -> (I, J), J <= I
  const int tb = blockIdx.x;
  int I = (int)((sqrtf(8.0f * tb + 1.0f) - 1.0f) * 0.5f);
  while ((I + 1) * (I + 2) / 2 <= tb) ++I;
  while (I * (I + 1) / 2 > tb) --I;
  const int J = tb - I * (I + 1) / 2;
  const int row0 = I * BMT;
  const int col0 = J * BMT;

  auto stage = [&](int kt) {
    const int r = tid & 127;
    const int shalf = tid >> 7;  // 0/1
    char* lbase = lds[kt & 1];
#pragma unroll
    for (int u = 0; u < 8; ++u) {
      const int q = u >> 1;
      const int s = (u & 1) * 2 + shalf;
      const int baserow = (q & 2) ? col0 : row0;
      const uint4* src = (q & 1) ? Lp : Hp;
      const uint4* gp = src + (size_t)(kt * 4 + s) * NB + baserow + r;
      GLD16(gp, lbase + u * 4096 + tid * 16);
    }
  };

  stage(0);
  __syncthreads();

  f32x4 acc[4][4];
#pragma unroll
  for (int m = 0; m < 4; ++m)
#pragma unroll
    for (int n = 0; n < 4; ++n) acc[m][n] = (f32x4){0.f, 0.f, 0.f, 0.f};

  for (int p = 0; p < NKT; ++p) {
    if (p + 1 < NKT) stage(p + 1);
    const char* base = lds[p & 1];
    const int aoff = g * 2048 + (wr * 64 + cl) * 16;
    const int boff = g * 2048 + (wc * 64 + cl) * 16;
    bf16x8 aH[4], bH[4], aL[4], bL[4];
    // pass 1: HH
#pragma unroll
    for (int m = 0; m < 4; ++m) aH[m] = *(const bf16x8*)(base + aoff + m * 256);
#pragma unroll
    for (int n = 0; n < 4; ++n) bH[n] = *(const bf16x8*)(base + 16384 + boff + n * 256);
#pragma unroll
    for (int m = 0; m < 4; ++m)
#pragma unroll
      for (int n = 0; n < 4; ++n)
        acc[m][n] = __builtin_amdgcn_mfma_f32_16x16x32_bf16(aH[m], bH[n], acc[m][n], 0, 0, 0);
    // pass 2: LH
#pragma unroll
    for (int m = 0; m < 4; ++m) aL[m] = *(const bf16x8*)(base + 8192 + aoff + m * 256);
#pragma unroll
    for (int m = 0; m < 4; ++m)
#pragma unroll
      for (int n = 0; n < 4; ++n)
        acc[m][n] = __builtin_amdgcn_mfma_f32_16x16x32_bf16(aL[m], bH[n], acc[m][n], 0, 0, 0);
    // pass 3: HL
#pragma unroll
    for (int n = 0; n < 4; ++n) bL[n] = *(const bf16x8*)(base + 24576 + boff + n * 256);
#pragma unroll
    for (int m = 0; m < 4; ++m)
#pragma unroll
      for (int n = 0; n < 4; ++n)
        acc[m][n] = __builtin_amdgcn_mfma_f32_16x16x32_bf16(aH[m], bL[n], acc[m][n], 0, 0, 0);
    __syncthreads();
  }

  // ---------------- epilogue: distances + dual mining ----------------
  float rsq[4][4]; int rtg[4][4];   // [m][i] : this lane's 16 rows
#pragma unroll
  for (int m = 0; m < 4; ++m)
#pragma unroll
    for (int i = 0; i < 4; ++i) {
      const int rr = row0 + wr * 64 + m * 16 + g * 4 + i;
      rsq[m][i] = sq[rr]; rtg[m][i] = targets[rr];
    }
  float csq[4]; int ctg[4];         // [n] : this lane's 4 cols
#pragma unroll
  for (int n = 0; n < 4; ++n) {
    const int cc = col0 + wc * 64 + n * 16 + cl;
    csq[n] = sq[cc]; ctg[n] = targets[cc];
  }
  // acc -> dist in place
#pragma unroll
  for (int m = 0; m < 4; ++m)
#pragma unroll
    for (int n = 0; n < 4; ++n)
#pragma unroll
      for (int i = 0; i < 4; ++i)
        acc[m][n][i] = sqrtf(fmaxf(rsq[m][i] + csq[n] - 2.0f * acc[m][n][i], FEPS));

  // -- row mining (per row, over this tile's 128 cols) --
  {
    float bap[16], ban[16]; int bapi[16], bani[16];
#pragma unroll
    for (int k = 0; k < 16; ++k) {
      bap[k] = -INFINITY; ban[k] = INFINITY; bapi[k] = 0; bani[k] = 0;
    }
#pragma unroll
    for (int n = 0; n < 4; ++n) {
      const int col = col0 + wc * 64 + n * 16 + cl;
#pragma unroll
      for (int m = 0; m < 4; ++m)
#pragma unroll
        for (int i = 0; i < 4; ++i) {
          const float d = acc[m][n][i];
          const int k16 = m * 4 + i;
          if (ctg[n] == rtg[m][i]) {
            if (d > bap[k16] || (d == bap[k16] && col < bapi[k16])) { bap[k16] = d; bapi[k16] = col; }
          } else {
            if (d < ban[k16] || (d == ban[k16] && col < bani[k16])) { ban[k16] = d; bani[k16] = col; }
          }
        }
    }
#pragma unroll
    for (int off = 1; off < 16; off <<= 1) {
#pragma unroll
      for (int k = 0; k < 16; ++k) {
        const float v = __shfl_xor(bap[k], off); const int vi = __shfl_xor(bapi[k], off);
        if (v > bap[k] || (v == bap[k] && vi < bapi[k])) { bap[k] = v; bapi[k] = vi; }
        const float u2 = __shfl_xor(ban[k], off); const int ui = __shfl_xor(bani[k], off);
        if (u2 < ban[k] || (u2 == ban[k] && ui < bani[k])) { ban[k] = u2; bani[k] = ui; }
      }
    }
    if (cl == 0) {
#pragma unroll
      for (int m = 0; m < 4; ++m)
#pragma unroll
        for (int i = 0; i < 4; ++i) {
          const int rl = wr * 64 + m * 16 + g * 4 + i;
          rowv[0][wc][rl] = bap[m * 4 + i]; rowi[0][wc][rl] = bapi[m * 4 + i];
          rowv[1][wc][rl] = ban[m * 4 + i]; rowi[1][wc][rl] = bani[m * 4 + i];
        }
    }
  }

  // -- col mining (per col, over this tile's 128 rows; transposed reduce) --
  {
    float cap[4], can[4]; int capi[4], cani[4];
#pragma unroll
    for (int n = 0; n < 4; ++n) { cap[n] = -INFINITY; can[n] = INFINITY; capi[n] = 0; cani[n] = 0; }
#pragma unroll
    for (int n = 0; n < 4; ++n) {
#pragma unroll
      for (int m = 0; m < 4; ++m)
#pragma unroll
        for (int i = 0; i < 4; ++i) {
          const int rr = row0 + wr * 64 + m * 16 + g * 4 + i;
          const float d = acc[m][n][i];
          if (rtg[m][i] == ctg[n]) {
            if (d > cap[n] || (d == cap[n] && rr < capi[n])) { cap[n] = d; capi[n] = rr; }
          } else {
            if (d < can[n] || (d == can[n] && rr < cani[n])) { can[n] = d; cani[n] = rr; }
          }
        }
    }
#pragma unroll
    for (int off = 16; off < 64; off <<= 1) {   // combine the 4 g-lanes per cl
#pragma unroll
      for (int n = 0; n < 4; ++n) {
        const float v = __shfl_xor(cap[n], off); const int vi = __shfl_xor(capi[n], off);
        if (v > cap[n] || (v == cap[n] && vi < capi[n])) { cap[n] = v; capi[n] = vi; }
        const float u2 = __shfl_xor(can[n], off); const int ui = __shfl_xor(cani[n], off);
        if (u2 < can[n] || (u2 == can[n] && ui < cani[n])) { can[n] = u2; cani[n] = ui; }
      }
    }
    if (g == 0) {
#pragma unroll
      for (int n = 0; n < 4; ++n) {
        const int c = wc * 64 + n * 16 + cl;
        colv[0][wr][c] = cap[n]; coli[0][wr][c] = capi[n];
        colv[1][wr][c] = can[n]; coli[1][wr][c] = cani[n];
      }
    }
  }

  __syncthreads();
  if (tid < BMT) {
    // row result: row (row0+tid), chunk J
    const int row = row0 + tid;
    float pv = rowv[0][0][tid]; int pi = rowi[0][0][tid];
    const float v1 = rowv[0][1][tid]; const int i1 = rowi[0][1][tid];
    if (v1 > pv || (v1 == pv && i1 < pi)) { pv = v1; pi = i1; }
    float nv = rowv[1][0][tid]; int ni = rowi[1][0][tid];
    const float v2 = rowv[1][1][tid]; const int i2 = rowi[1][1][tid];
    if (v2 < nv || (v2 == nv && i2 < ni)) { nv = v2; ni = i2; }
    pap[row * NCHUNK + J] = pv; papi[row * NCHUNK + J] = pi;
    pan[row * NCHUNK + J] = nv; pani[row * NCHUNK + J] = ni;
  } else if (I != J) {
    // col result: row (col0 + c), chunk I
    const int c = tid - BMT;
    const int row = col0 + c;
    float pv = colv[0][0][c]; int pi = coli[0][0][c];
    const float v1 = colv[0][1][c]; const int i1 = coli[0][1][c];
    if (v1 > pv || (v1 == pv && i1 < pi)) { pv = v1; pi = i1; }
    float nv = colv[1][0][c]; int ni = coli[1][0][c];
    const float v2 = colv[1][1][c]; const int i2 = coli[1][1][c];
    if (v2 < nv || (v2 == nv && i2 < ni)) { nv = v2; ni = i2; }
    pap[row * NCHUNK + I] = pv; papi[row * NCHUNK + I] = pi;
    pan[row * NCHUNK + I] = nv; pani[row * NCHUNK + I] = ni;
  }
}

// ---------------- kernel 3: reduce the 32 per-chunk partials ----------------
__global__ __launch_bounds__(256) void mine_reduce_kernel(
    const float* __restrict__ pap, const int* __restrict__ papi,
    const float* __restrict__ pan, const int* __restrict__ pani,
    float* __restrict__ dap, float* __restrict__ dan,
    int* __restrict__ pidx, int* __restrict__ nidx) {
  const int row = blockIdx.x * 256 + threadIdx.x;
  if (row >= NB) return;
  float bap = -INFINITY, ban = INFINITY;
  int bapi = 0, bani = 0;
#pragma unroll
  for (int c = 0; c < NCHUNK; ++c) {
    const float v = pap[row * NCHUNK + c]; const int i2 = papi[row * NCHUNK + c];
    if (v > bap || (v == bap && i2 < bapi)) { bap = v; bapi = i2; }
    const float w = pan[row * NCHUNK + c]; const int j2 = pani[row * NCHUNK + c];
    if (w < ban || (w == ban && j2 < bani)) { ban = w; bani = j2; }
  }
  dap[row] = bap; dan[row] = ban; pidx[row] = bapi; nidx[row] = bani;
}

// ---- kernel 4: aligned local distance (8x8 DTW DP), pos+neg fused ---------
__global__ __launch_bounds__(128) void local_dist_kernel(
    const float* __restrict__ lf,   // [N][C=128][P=8]
    const int* __restrict__ pidx, const int* __restrict__ nidx,
    float* __restrict__ lap, float* __restrict__ lan) {
  const int i = blockIdx.x;
  __shared__ float X[CLOC * PARTS];
  __shared__ float Y[2][CLOC * PARTS];
  __shared__ float DM[2][64];
  const int t = threadIdx.x;
  const int h = t >> 6, tl = t & 63;       // h=0: positive, h=1: negative
  const int j = (h == 0) ? pidx[i] : nidx[i];
  const float* xi = lf + (size_t)i * (CLOC * PARTS);
  const float* yj = lf + (size_t)j * (CLOC * PARTS);
  for (int e = t; e < CLOC * PARTS; e += 128) X[e] = xi[e];
  for (int e = tl; e < CLOC * PARTS; e += 64) Y[h][e] = yj[e];
  __syncthreads();
  const int p = tl >> 3, q = tl & 7;
  float xx = 0.f, yy = 0.f, xy = 0.f;
#pragma unroll 8
  for (int c = 0; c < CLOC; ++c) {
    const float xv = X[c * 8 + p], yv = Y[h][c * 8 + q];
    xx += xv * xv; yy += yv * yv; xy += xv * yv;
  }
  const float d2 = xx + yy - 2.0f * xy;
  const float dist = sqrtf(fmaxf(d2, FEPS));
  DM[h][p * 8 + q] = tanhf(0.5f * dist);
  __syncthreads();
  if (tl == 0) {
    const float* dm = DM[h];
    float row[8];
    row[0] = dm[0];
    for (int c = 1; c < 8; ++c) row[c] = row[c - 1] + dm[c];
    for (int r = 1; r < 8; ++r) {
      row[0] += dm[r * 8];
      for (int c = 1; c < 8; ++c) row[c] = fminf(row[c], row[c - 1]) + dm[r * 8 + c];
    }
    ((h == 0) ? lap : lan)[i] = row[7];
  }
}

// ---------------- kernel 5: margin ranking losses (means) ------------------
__global__ __launch_bounds__(256) void loss_kernel(
    const float* __restrict__ dap, const float* __restrict__ dan,
    const float* __restrict__ lap, const float* __restrict__ lan,
    float* __restrict__ out) {
  __shared__ float sm1[4], sm2[4];
  const int t = threadIdx.x;
  float s1 = 0.f, s2 = 0.f;
  for (int i = t; i < NB; i += 256) {
    s1 += fmaxf(0.f, FMARGIN - (dan[i] - dap[i]));
    s2 += fmaxf(0.f, FMARGIN - (lan[i] - lap[i]));
  }
  for (int off = 32; off; off >>= 1) { s1 += __shfl_down(s1, off); s2 += __shfl_down(s2, off); }
  const int lane = t & 63, wid = t >> 6;
  if (lane == 0) { sm1[wid] = s1; sm2[wid] = s2; }
  __syncthreads();
  if (t == 0) {
    out[0] = (sm1[0] + sm1[1] + sm1[2] + sm1[3]) * (1.0f / NB);
    out[1] = (sm2[0] + sm2[1] + sm2[2] + sm2[3]) * (1.0f / NB);
  }
}

extern "C" void kernel_launch(void* const* d_in, const int* in_sizes, int n_in,
                              void* d_out, int out_size, void* d_ws, size_t ws_size,
                              hipStream_t stream) {
  const float* inputs = (const float*)d_in[0];
  const int* targets = (const int*)d_in[1];
  const float* localf = (const float*)d_in[2];
  float* out = (float*)d_out;

  // workspace carve (~34.2 MB)
  uint4* Hp  = (uint4*)d_ws;                       // 256*4096 uint4 = 16 MB
  uint4* Lp  = Hp + (size_t)(DD / 8) * NB;         // 16 MB
  float* sq  = (float*)(Lp + (size_t)(DD / 8) * NB);
  float* pap = sq + NB;
  int*   papi = (int*)(pap + (size_t)NB * NCHUNK);
  float* pan  = (float*)(papi + (size_t)NB * NCHUNK);
  int*   pani = (int*)(pan + (size_t)NB * NCHUNK);
  float* dap  = (float*)(pani + (size_t)NB * NCHUNK);
  float* dan  = dap + NB;
  int*   pidx = (int*)(dan + NB);
  int*   nidx = pidx + NB;
  float* lap  = (float*)(nidx + NB);
  float* lan  = lap + NB;

  normalize_pack_kernel<<<NB / 4, 256, 0, stream>>>(inputs, Hp, Lp, sq);
  dist_mine_mfma<<<NTILES, 256, 0, stream>>>(Hp, Lp, sq, targets,
                                             pap, papi, pan, pani);
  mine_reduce_kernel<<<NB / 256, 256, 0, stream>>>(pap, papi, pan, pani, dap, dan, pidx, nidx);
  local_dist_kernel<<<NB, 128, 0, stream>>>(localf, pidx, nidx, lap, lan);
  loss_kernel<<<1, 256, 0, stream>>>(dap, dan, lap, lan, out);
}